// Round 5
// baseline (336.314 us; speedup 1.0000x reference)
//
#include <hip/hip_runtime.h>
#include <hip/hip_bf16.h>
#include <stdint.h>

#define S_LEN 2048
#define HDIM  2048
#define NHQ   16
#define NKVH  4
#define HD    128
#define WIN   1024
#define QKV_N 3072          // 2048 q | 512 k | 512 v
#define SM_SCALE 0.08838834764831845f
#define NEG_BIG  -1.0e30f

typedef __attribute__((ext_vector_type(8))) short short8;
typedef __attribute__((ext_vector_type(4))) float float4v;
typedef unsigned short u16;

static __device__ __forceinline__ float bf2f(u16 u) {
  union { unsigned int i; float f; } v; v.i = ((unsigned int)u) << 16; return v.f;
}
static __device__ __forceinline__ u16 f2bf(float f) {
  union { float f; unsigned int i; } v; v.f = f;
  unsigned int x = v.i;
  return (u16)((x + 0x7fffu + ((x >> 16) & 1u)) >> 16);   // RNE, finite inputs
}

// ---------------------------------------------------------------------------
// fp32 -> bf16 elementwise convert (hidden_state). n divisible by 1024.
// ---------------------------------------------------------------------------
__global__ __launch_bounds__(256) void cvt_f32_bf16(
    const float* __restrict__ x, u16* __restrict__ y, int n)
{
  const int i = (blockIdx.x * 256 + threadIdx.x) * 4;
  if (i < n) {
    const float4 v = *(const float4*)(x + i);
    y[i + 0] = f2bf(v.x);
    y[i + 1] = f2bf(v.y);
    y[i + 2] = f2bf(v.z);
    y[i + 3] = f2bf(v.w);
  }
}

// ---------------------------------------------------------------------------
// Fused convert+transpose: W fp32 [K][N] -> WT bf16 [N][K].
// ---------------------------------------------------------------------------
__global__ __launch_bounds__(256) void transpose_f32_bf16(
    const float* __restrict__ W, u16* __restrict__ WT, int K, int N)
{
  __shared__ u16 t[32][33];
  const int n0 = blockIdx.x * 32, k0 = blockIdx.y * 32;
  const int tx = threadIdx.x & 31, ty = threadIdx.x >> 5;
#pragma unroll
  for (int i = 0; i < 4; ++i)
    t[ty + i * 8][tx] = f2bf(W[(size_t)(k0 + ty + i * 8) * N + n0 + tx]);
  __syncthreads();
#pragma unroll
  for (int i = 0; i < 4; ++i)
    WT[(size_t)(n0 + ty + i * 8) * K + k0 + tx] = t[tx][ty + i * 8];
}

// ---------------------------------------------------------------------------
// GEMM: C = A[M,K] * BT[N,K]^T, bf16 in, fp32 accum. m97 template.
// OUT_F32 selects output dtype (final projection writes fp32 d_out).
// ---------------------------------------------------------------------------
template <bool OUT_F32>
__global__ __launch_bounds__(256) void gemm_bt(
    const u16* __restrict__ A, const u16* __restrict__ BT,
    void* __restrict__ Cv, int M, int N, int K)
{
  __shared__ u16 Als[128 * 32];
  __shared__ u16 Bls[128 * 32];

  const int tid  = threadIdx.x;
  const int lane = tid & 63;
  const int w    = tid >> 6;
  const int quad = lane >> 4;
  const int lc   = lane & 15;
  const int n0   = blockIdx.x * 128;
  const int m0   = blockIdx.y * 128;
  const int wr   = (w >> 1) * 64;
  const int wc   = (w & 1) * 64;

  float4v acc[4][4];
#pragma unroll
  for (int i = 0; i < 4; ++i)
#pragma unroll
    for (int j = 0; j < 4; ++j) acc[i][j] = (float4v){0.f, 0.f, 0.f, 0.f};

  const int offBase = w * 1024 + lane * 16;

  for (int k0 = 0; k0 < K; k0 += 32) {
    __syncthreads();
#pragma unroll
    for (int r = 0; r < 2; ++r) {
      const int off  = r * 4096 + offBase;
      const int row  = off >> 6;
      const int colb = off & 63;
      const u16* ga = A  + (size_t)(m0 + row) * K + k0 + (colb >> 1);
      const u16* gb = BT + (size_t)(n0 + row) * K + k0 + (colb >> 1);
      __builtin_amdgcn_global_load_lds(
          (__attribute__((address_space(1))) void*)ga,
          (__attribute__((address_space(3))) void*)((char*)Als + r * 4096 + w * 1024),
          16, 0, 0);
      __builtin_amdgcn_global_load_lds(
          (__attribute__((address_space(1))) void*)gb,
          (__attribute__((address_space(3))) void*)((char*)Bls + r * 4096 + w * 1024),
          16, 0, 0);
    }
    __syncthreads();

    short8 af[4], bfr[4];
#pragma unroll
    for (int mi = 0; mi < 4; ++mi)
      af[mi] = *(const short8*)(Als + (wr + mi * 16 + lc) * 32 + quad * 8);
#pragma unroll
    for (int ni = 0; ni < 4; ++ni)
      bfr[ni] = *(const short8*)(Bls + (wc + ni * 16 + lc) * 32 + quad * 8);
#pragma unroll
    for (int mi = 0; mi < 4; ++mi)
#pragma unroll
      for (int ni = 0; ni < 4; ++ni)
        acc[mi][ni] = __builtin_amdgcn_mfma_f32_16x16x32_bf16(
            af[mi], bfr[ni], acc[mi][ni], 0, 0, 0);
  }

#pragma unroll
  for (int mi = 0; mi < 4; ++mi)
#pragma unroll
    for (int ni = 0; ni < 4; ++ni)
#pragma unroll
      for (int r = 0; r < 4; ++r) {
        const int row = m0 + wr + mi * 16 + quad * 4 + r;
        const int col = n0 + wc + ni * 16 + lc;
        if (OUT_F32)
          ((float*)Cv)[(size_t)row * N + col] = acc[mi][ni][r];
        else
          ((u16*)Cv)[(size_t)row * N + col] = f2bf(acc[mi][ni][r]);
      }
}

// ---------------------------------------------------------------------------
// RoPE in-place on QKV (q cols 0..2047, k cols 2048..2559). fc fp32 [S][64][2].
// ---------------------------------------------------------------------------
__global__ __launch_bounds__(256) void rope_kernel(
    u16* __restrict__ qkv, const float* __restrict__ fc)
{
  const int id   = blockIdx.x * 256 + threadIdx.x;   // S*20*64 total
  const int d    = id & 63;
  const int rest = id >> 6;
  const int head = rest % 20;
  const int s    = rest / 20;
  const int col  = (head < 16) ? head * 128 + 2 * d
                               : 2048 + (head - 16) * 128 + 2 * d;
  u16* p = qkv + (size_t)s * QKV_N + col;
  const float a = bf2f(p[0]);
  const float b = bf2f(p[1]);
  const float c  = fc[s * 128 + d * 2 + 0];
  const float sn = fc[s * 128 + d * 2 + 1];
  p[0] = f2bf(a * c - b * sn);
  p[1] = f2bf(a * sn + b * c);
}

// ---------------------------------------------------------------------------
// Flash attention, sliding window 1024, GQA 4:1. All-finite arithmetic.
// grid = (S/64, NH), 256 threads = 4 waves; wave w owns q rows [q0+16w .. +15].
// ---------------------------------------------------------------------------
__global__ __launch_bounds__(256) void attn_kernel(
    const u16* __restrict__ qkv, u16* __restrict__ out)
{
  __shared__ u16 VT[128 * 72];        // [hd][key], stride 72 (pad 8)
  __shared__ u16 P[4 * 16 * 72];      // per-wave P strips [w*16+m][key]

  const int tid  = threadIdx.x;
  const int lane = tid & 63;
  const int w    = tid >> 6;
  const int quad = lane >> 4;
  const int lc   = lane & 15;
  const int q0   = blockIdx.x * 64;
  const int h    = blockIdx.y;
  const int kvh  = h >> 2;
  const int rb   = q0 + w * 16;

  short8 qf[4];
  {
    const u16* qp = qkv + (size_t)(rb + lc) * QKV_N + h * HD + quad * 8;
#pragma unroll
    for (int ks = 0; ks < 4; ++ks) qf[ks] = *(const short8*)(qp + ks * 32);
  }

  float4v o[8];
#pragma unroll
  for (int i = 0; i < 8; ++i) o[i] = (float4v){0.f, 0.f, 0.f, 0.f};
  float mrow[4], lrow[4];
#pragma unroll
  for (int r = 0; r < 4; ++r) { mrow[r] = NEG_BIG; lrow[r] = 0.f; }

  const int kt_begin = (q0 >= WIN - 1) ? ((q0 - (WIN - 1)) >> 6) : 0;
  const int kt_end   = q0 >> 6;

  for (int kt = kt_begin; kt <= kt_end; ++kt) {
    const int k0 = kt * 64;

    __syncthreads();
#pragma unroll
    for (int cc = 0; cc < 4; ++cc) {
      const int c   = tid * 4 + cc;
      const int key = c >> 4;
      const int hd8 = (c & 15) * 8;
      short8 v = *(const short8*)(qkv + (size_t)(k0 + key) * QKV_N + 2560 + kvh * HD + hd8);
#pragma unroll
      for (int j = 0; j < 8; ++j) VT[(hd8 + j) * 72 + key] = (u16)v[j];
    }
    __syncthreads();

    float4v sacc[4];
#pragma unroll
    for (int i = 0; i < 4; ++i) sacc[i] = (float4v){0.f, 0.f, 0.f, 0.f};
#pragma unroll
    for (int ks = 0; ks < 4; ++ks) {
#pragma unroll
      for (int nt = 0; nt < 4; ++nt) {
        const u16* kp = qkv + (size_t)(k0 + nt * 16 + lc) * QKV_N + 2048 + kvh * HD
                        + ks * 32 + quad * 8;
        short8 kb = *(const short8*)kp;
        sacc[nt] = __builtin_amdgcn_mfma_f32_16x16x32_bf16(qf[ks], kb, sacc[nt], 0, 0, 0);
      }
    }

    const bool full = (k0 + 63 <= rb) && ((rb + 15 - k0) <= WIN - 1);
    float sv[4][4];
    bool  ok[4][4];
    float rmax[4] = {NEG_BIG, NEG_BIG, NEG_BIG, NEG_BIG};
#pragma unroll
    for (int nt = 0; nt < 4; ++nt) {
      const int j = k0 + nt * 16 + lc;
#pragma unroll
      for (int r = 0; r < 4; ++r) {
        const int i = rb + quad * 4 + r;
        const bool valid = full || ((j <= i) && (i - j < WIN));
        float s = sacc[nt][r] * SM_SCALE;
        s = valid ? s : NEG_BIG;
        sv[nt][r] = s;
        ok[nt][r] = valid;
        rmax[r] = fmaxf(rmax[r], s);
      }
    }
#pragma unroll
    for (int off = 1; off < 16; off <<= 1)
#pragma unroll
      for (int r = 0; r < 4; ++r)
        rmax[r] = fmaxf(rmax[r], __shfl_xor(rmax[r], off, 64));

    float alpha[4], rsum[4];
#pragma unroll
    for (int r = 0; r < 4; ++r) {
      const float mn = fmaxf(mrow[r], rmax[r]);
      alpha[r] = __expf(mrow[r] - mn);
      mrow[r] = mn;
      rsum[r] = 0.f;
    }
#pragma unroll
    for (int nt = 0; nt < 4; ++nt)
#pragma unroll
      for (int r = 0; r < 4; ++r) {
        const float p = ok[nt][r] ? __expf(sv[nt][r] - mrow[r]) : 0.f;
        rsum[r] += p;
        P[(w * 16 + quad * 4 + r) * 72 + nt * 16 + lc] = f2bf(p);
      }
#pragma unroll
    for (int off = 1; off < 16; off <<= 1)
#pragma unroll
      for (int r = 0; r < 4; ++r)
        rsum[r] += __shfl_xor(rsum[r], off, 64);
#pragma unroll
    for (int r = 0; r < 4; ++r) lrow[r] = lrow[r] * alpha[r] + rsum[r];
#pragma unroll
    for (int i = 0; i < 8; ++i)
#pragma unroll
      for (int r = 0; r < 4; ++r) o[i][r] *= alpha[r];

#pragma unroll
    for (int ktk = 0; ktk < 2; ++ktk) {
      short8 pa = *(const short8*)(P + (w * 16 + lc) * 72 + ktk * 32 + quad * 8);
#pragma unroll
      for (int nt2 = 0; nt2 < 8; ++nt2) {
        short8 vb = *(const short8*)(VT + (nt2 * 16 + lc) * 72 + ktk * 32 + quad * 8);
        o[nt2] = __builtin_amdgcn_mfma_f32_16x16x32_bf16(pa, vb, o[nt2], 0, 0, 0);
      }
    }
  }

#pragma unroll
  for (int r = 0; r < 4; ++r) {
    const float inv = (lrow[r] > 0.f) ? (1.f / lrow[r]) : 0.f;
#pragma unroll
    for (int nt2 = 0; nt2 < 8; ++nt2) {
      const int row = rb + quad * 4 + r;
      const int col = h * HD + nt2 * 16 + lc;
      out[(size_t)row * 2048 + col] = f2bf(o[nt2][r] * inv);
    }
  }
}

// ---------------------------------------------------------------------------
extern "C" void kernel_launch(void* const* d_in, const int* in_sizes, int n_in,
                              void* d_out, int out_size, void* d_ws, size_t ws_size,
                              hipStream_t stream) {
  const float* hs = (const float*)d_in[0];   // fp32
  const float* fc = (const float*)d_in[1];   // fp32
  // d_in[2] attention_mask all-true; d_in[3] causal analytic; d_in[4] arange
  const float* Wq = (const float*)d_in[5];
  const float* Wk = (const float*)d_in[6];
  const float* Wv = (const float*)d_in[7];
  const float* Wo = (const float*)d_in[8];
  float* outp = (float*)d_out;               // fp32 output (reference dtype)

  u16* hsB   = (u16*)d_ws;                           // 2048 x 2048 bf16
  u16* WqkvT = hsB   + (size_t)2048 * 2048;          // 3072 x 2048
  u16* WoT   = WqkvT + (size_t)3072 * 2048;          // 2048 x 2048
  u16* QKV   = WoT   + (size_t)2048 * 2048;          // 2048 x 3072
  u16* ATTN  = QKV   + (size_t)2048 * 3072;          // 2048 x 2048

  dim3 blk(256);
  cvt_f32_bf16<<<dim3(2048 * 2048 / 1024), blk, 0, stream>>>(hs, hsB, 2048 * 2048);
  transpose_f32_bf16<<<dim3(2048 / 32, 2048 / 32), blk, 0, stream>>>(Wq, WqkvT, 2048, 2048);
  transpose_f32_bf16<<<dim3(512 / 32, 2048 / 32), blk, 0, stream>>>(Wk, WqkvT + (size_t)2048 * 2048, 2048, 512);
  transpose_f32_bf16<<<dim3(512 / 32, 2048 / 32), blk, 0, stream>>>(Wv, WqkvT + (size_t)2560 * 2048, 2048, 512);
  transpose_f32_bf16<<<dim3(2048 / 32, 2048 / 32), blk, 0, stream>>>(Wo, WoT, 2048, 2048);

  gemm_bt<false><<<dim3(3072 / 128, 2048 / 128), blk, 0, stream>>>(hsB, WqkvT, QKV, 2048, 3072, 2048);
  rope_kernel<<<dim3(2048 * 1280 / 256), blk, 0, stream>>>(QKV, fc);
  attn_kernel<<<dim3(2048 / 64, NHQ), blk, 0, stream>>>(QKV, ATTN);
  gemm_bt<true><<<dim3(2048 / 128, 2048 / 128), blk, 0, stream>>>(ATTN, WoT, outp, 2048, 2048, 2048);
}